// Round 6
// baseline (157.954 us; speedup 1.0000x reference)
//
#include <hip/hip_runtime.h>
#include <stdint.h>

#define HW 65536   // 256*256
#define C_ 64

typedef __attribute__((ext_vector_type(8))) short short8;
typedef __attribute__((ext_vector_type(4))) float f32x4;
typedef long long i64;

#define MFMA16(a, b, c) __builtin_amdgcn_mfma_f32_16x16x32_bf16((a), (b), (c), 0, 0, 0)
#define MFMA8(a, b, c)  __builtin_amdgcn_mfma_f32_16x16x32_fp8_fp8((a), (b), (c), 0, 0, 0)

union U16x8 { uint4 q; short8 v; uint32_t u[4]; };
union PU { uint32_t u[2]; i64 q; };

__device__ inline uint32_t pack_bf16(float lo, float hi) {
  uint32_t ul = __float_as_uint(lo), uh = __float_as_uint(hi);
  ul = (ul + 0x7fffu + ((ul >> 16) & 1u)) >> 16;
  uh = (uh + 0x7fffu + ((uh >> 16) & 1u)) >> 16;
  return ul | (uh << 16);
}
__device__ inline short8 ld8bf(const uint16_t* p) {
  U16x8 t; t.q = *(const uint4*)p; return t.v;
}
__device__ inline i64 ld8f8(const uint8_t* p) { return *(const i64*)p; }
// P loads must use the SAME type as P stores (uint32_t) so the compiler keeps
// program order vs the ds_writes in the same phase (TBAA).
__device__ inline i64 ldP(const uint8_t* p) {
  PU t;
  t.u[0] = *(const uint32_t*)p;
  t.u[1] = *(const uint32_t*)(p + 4);
  return t.q;
}
__device__ inline uint32_t pk4f8(float a, float b, float c, float d) {
  uint32_t v = __builtin_amdgcn_cvt_pk_fp8_f32(a, b, 0, false);
  v = __builtin_amdgcn_cvt_pk_fp8_f32(c, d, v, true);
  return v;
}

// bf16 X tile: elem index, XOR swizzle (8-elem granule)
__device__ inline int xb_idx(int p, int c) { return (p * 64 + c) ^ ((p & 7) << 3); }
// fp8 Q/S tile: byte index [pix][c]
__device__ inline int qf_idx(int p, int c) { return p * 64 + (c ^ ((p & 7) << 3)); }
// fp8 V tile: byte offset [c][j]
__device__ inline int vf_idx(int c, int j) { return c * 256 + (j ^ ((c & 7) << 3)); }

__global__ __launch_bounds__(512, 4) void SCAM_73151882985874_kernel(
    const float* __restrict__ x, const float* __restrict__ res_enc,
    const float* __restrict__ tr_feat,
    const float* __restrict__ Wl1, const float* __restrict__ bl1,
    const float* __restrict__ Wr1, const float* __restrict__ br1,
    const float* __restrict__ Wl2, const float* __restrict__ bl2,
    const float* __restrict__ Wr2, const float* __restrict__ br2,
    const float* __restrict__ beta1, const float* __restrict__ gamma1,
    const float* __restrict__ beta3, const float* __restrict__ gamma3,
    float* __restrict__ out)
{
  // A1: xl bf16 [pix][c] (32KB)  ->  Q fp8 [pix][c] (16KB) | bufL fp8 [c][j] (16KB)
  // A2: xr bf16 [pix][c] (32KB)  ->  S fp8 [pix][c] (16KB) | bufR fp8 [c][j] (16KB)
  __shared__ __align__(16) uint8_t A1[32768];
  __shared__ __align__(16) uint8_t A2[32768];
  __shared__ __align__(16) uint8_t sP8[10240];   // per-wave P fp8: 8 x [32 cols][40 B]

  const int tid = threadIdx.x;
  const int wid = tid >> 6, lane = tid & 63, g = lane >> 4, li = lane & 15;
  const int bb = blockIdx.x >> 8, hh = blockIdx.x & 255;
  const float yy = (float)hh * (2.0f / 255.0f) - 1.0f;
  const float rr = fabsf(yy - 0.5f);

  const size_t rowoff = (size_t)hh * 256;
  const float* xl  = x + ((size_t)bb * C_) * HW + rowoff;
  const float* xr  = x + ((size_t)(2 + bb) * C_) * HW + rowoff;
  const float* trl = tr_feat + ((size_t)bb * C_) * HW + rowoff;
  const float* trr = tr_feat + ((size_t)(2 + bb) * C_) * HW + rowoff;
  const float* rel = res_enc + ((size_t)bb * C_) * HW + rowoff;
  const float* rer = res_enc + ((size_t)(2 + bb) * C_) * HW + rowoff;
  float* outL = out + ((size_t)bb * C_) * HW + rowoff;
  float* outR = out + ((size_t)(2 + bb) * C_) * HW + rowoff;

  // ---------- Phase A: stage xl -> A1, xr -> A2 (f32 -> bf16 [pix][c]) ----------
  {
    const int side = tid >> 8;
    const int p    = tid & 255;
    const float* src = side ? xr : xl;
    uint16_t* dst = (uint16_t*)(side ? A2 : A1);
    #pragma unroll
    for (int cb = 0; cb < 8; ++cb) {
      int c0 = cb * 8;
      const float* s = src + (size_t)c0 * HW + p;
      U16x8 t8;
      t8.u[0] = pack_bf16(s[0],              s[(size_t)HW]);
      t8.u[1] = pack_bf16(s[2 * (size_t)HW], s[3 * (size_t)HW]);
      t8.u[2] = pack_bf16(s[4 * (size_t)HW], s[5 * (size_t)HW]);
      t8.u[3] = pack_bf16(s[6 * (size_t)HW], s[7 * (size_t)HW]);
      *(uint4*)&dst[xb_idx(p, c0)] = t8.q;
    }
  }
  __syncthreads();

  // own-X fragments -> regs (must complete block-wide before fp8 overwrites)
  short8 bxL[2][2], bxR[2][2];
  #pragma unroll
  for (int ptl = 0; ptl < 2; ++ptl) {
    int pix = wid * 32 + ptl * 16 + li;
    bxL[ptl][0] = ld8bf(&((const uint16_t*)A1)[xb_idx(pix, g * 8)]);
    bxL[ptl][1] = ld8bf(&((const uint16_t*)A1)[xb_idx(pix, 32 + g * 8)]);
    bxR[ptl][0] = ld8bf(&((const uint16_t*)A2)[xb_idx(pix, g * 8)]);
    bxR[ptl][1] = ld8bf(&((const uint16_t*)A2)[xb_idx(pix, 32 + g * 8)]);
  }
  __syncthreads();

  // ---------- Phase B: four 1x1 convs (bf16 MFMA), outputs quantized to fp8 ----------
  auto conv_one = [&](const float* __restrict__ Wm, int ldw,
                      const float* __restrict__ bias, const float* __restrict__ mod,
                      const float* __restrict__ E, int coord,
                      const short8 bx[2][2], uint8_t* dstQS, uint8_t* dstV) {
    short8 af[4][2];
    #pragma unroll
    for (int ct = 0; ct < 4; ++ct) {
      const float* wr = Wm + (size_t)(ct * 16 + li) * ldw + g * 8;
      U16x8 t8;
      t8.u[0] = pack_bf16(wr[0], wr[1]); t8.u[1] = pack_bf16(wr[2], wr[3]);
      t8.u[2] = pack_bf16(wr[4], wr[5]); t8.u[3] = pack_bf16(wr[6], wr[7]);
      af[ct][0] = t8.v;
      const float* w2 = wr + 32;
      t8.u[0] = pack_bf16(w2[0], w2[1]); t8.u[1] = pack_bf16(w2[2], w2[3]);
      t8.u[2] = pack_bf16(w2[4], w2[5]); t8.u[3] = pack_bf16(w2[6], w2[7]);
      af[ct][1] = t8.v;
    }
    float be[4][4], md[4][4];
    #pragma unroll
    for (int ct = 0; ct < 4; ++ct)
      #pragma unroll
      for (int r = 0; r < 4; ++r) {
        int c = ct * 16 + 4 * g + r;
        float b = bias[c];
        if (coord) b += Wm[(size_t)c * ldw + 64] * yy + Wm[(size_t)c * ldw + 65] * rr;
        be[ct][r] = b;
        md[ct][r] = mod[c];
      }
    #pragma unroll
    for (int ptl = 0; ptl < 2; ++ptl) {
      int pix = wid * 32 + ptl * 16 + li;
      #pragma unroll
      for (int ct = 0; ct < 4; ++ct) {
        float ev[4];
        #pragma unroll
        for (int r = 0; r < 4; ++r)
          ev[r] = E[(size_t)(ct * 16 + 4 * g + r) * HW + pix];
        f32x4 acc = {0.f, 0.f, 0.f, 0.f};
        acc = MFMA16(af[ct][0], bx[ptl][0], acc);
        acc = MFMA16(af[ct][1], bx[ptl][1], acc);
        float v[4];
        #pragma unroll
        for (int r = 0; r < 4; ++r) v[r] = acc[r] + be[ct][r] + md[ct][r] * ev[r];
        if (dstV) {
          uint32_t pk = pk4f8(v[0], v[1], v[2], v[3]);
          #pragma unroll
          for (int r = 0; r < 4; ++r)
            dstV[vf_idx(ct * 16 + 4 * g + r, pix)] = (uint8_t)(pk >> (8 * r));
        } else {
          *(uint32_t*)&dstQS[qf_idx(pix, ct * 16 + 4 * g)] = pk4f8(v[0], v[1], v[2], v[3]);
        }
      }
    }
  };

  conv_one(Wl1, 66, bl1, beta1,  trl, 1, bxL, A1, nullptr);         // Q   (fp8, unscaled)
  conv_one(Wr1, 66, br1, beta1,  trr, 1, bxR, A2, nullptr);         // S
  conv_one(Wl2, 64, bl2, gamma1, rel, 0, bxL, nullptr, A1 + 16384); // bufL
  conv_one(Wr2, 64, br2, gamma1, rer, 0, bxR, nullptr, A2 + 16384); // bufR
  __syncthreads();

  uint8_t* Pw = &sP8[wid * 1280];
  const int j0 = wid * 32;

  // ---------- pass 2: out_R cols = own 32 pixels; sum over a >= col ----------
  {
    i64 bS[2][2];
    #pragma unroll
    for (int jt = 0; jt < 2; ++jt) {
      int p = j0 + jt * 16 + li;
      bS[jt][0] = ld8f8(&A2[qf_idx(p, g * 8)]);
      bS[jt][1] = ld8f8(&A2[qf_idx(p, 32 + g * 8)]);
    }
    f32x4 acc[4][2];
    #pragma unroll
    for (int ct = 0; ct < 4; ++ct) { acc[ct][0] = (f32x4){0,0,0,0}; acc[ct][1] = (f32x4){0,0,0,0}; }
    float zp0 = 0.f, zp1 = 0.f;

    for (int ip = wid; ip < 8; ++ip) {
      i64 aQ[2][2];
      #pragma unroll
      for (int itl = 0; itl < 2; ++itl) {
        int arow = ip * 32 + itl * 16 + li;
        aQ[itl][0] = ld8f8(&A1[qf_idx(arow, g * 8)]);
        aQ[itl][1] = ld8f8(&A1[qf_idx(arow, 32 + g * 8)]);
      }
      #pragma unroll
      for (int itl = 0; itl < 2; ++itl)
        #pragma unroll
        for (int jt = 0; jt < 2; ++jt) {
          f32x4 s = {0.f, 0.f, 0.f, 0.f};
          s = MFMA8(aQ[itl][0], bS[jt][0], s);
          s = MFMA8(aQ[itl][1], bS[jt][1], s);
          int jj = j0 + jt * 16 + li;
          float p4[4]; float ps = 0.f;
          #pragma unroll
          for (int r = 0; r < 4; ++r) {
            int aidx = ip * 32 + itl * 16 + 4 * g + r;
            p4[r] = (aidx >= jj) ? __expf(s[r] * 0.125f) : 0.f;
            ps += p4[r];
          }
          if (jt == 0) zp0 += ps; else zp1 += ps;
          *(uint32_t*)&Pw[(jt * 16 + li) * 40 + itl * 16 + 4 * g] =
              pk4f8(p4[0], p4[1], p4[2], p4[3]);
        }
      asm volatile("" ::: "memory");   // order P reads after P writes
      i64 aV[4];
      #pragma unroll
      for (int ct = 0; ct < 4; ++ct)
        aV[ct] = ld8f8(&A1[16384 + vf_idx(ct * 16 + li, ip * 32 + g * 8)]);
      #pragma unroll
      for (int jt = 0; jt < 2; ++jt) {
        i64 bP = ldP(&Pw[(jt * 16 + li) * 40 + g * 8]);
        #pragma unroll
        for (int ct = 0; ct < 4; ++ct)
          acc[ct][jt] = MFMA8(aV[ct], bP, acc[ct][jt]);
      }
    }
    zp0 += __shfl_xor(zp0, 16); zp0 += __shfl_xor(zp0, 32);
    zp1 += __shfl_xor(zp1, 16); zp1 += __shfl_xor(zp1, 32);
    #pragma unroll
    for (int jt = 0; jt < 2; ++jt) {
      float invz = 1.0f / (jt == 0 ? zp0 : zp1);
      int j = j0 + jt * 16 + li;
      #pragma unroll
      for (int ct = 0; ct < 4; ++ct)
        #pragma unroll
        for (int r = 0; r < 4; ++r) {
          int c = ct * 16 + 4 * g + r;
          outR[(size_t)c * HW + j] =
              fmaf(gamma3[c], acc[ct][jt][r] * invz, xr[(size_t)c * HW + j]);
        }
    }
  }

  // ---------- pass 1: out_L cols = own 32 pixels; sum over a <= col ----------
  // (no barrier: Q/S/V regions read-only since conv barrier; Pw wave-private)
  {
    i64 bQ[2][2];
    #pragma unroll
    for (int itl = 0; itl < 2; ++itl) {
      int p = j0 + itl * 16 + li;
      bQ[itl][0] = ld8f8(&A1[qf_idx(p, g * 8)]);
      bQ[itl][1] = ld8f8(&A1[qf_idx(p, 32 + g * 8)]);
    }
    f32x4 acc[4][2];
    #pragma unroll
    for (int ct = 0; ct < 4; ++ct) { acc[ct][0] = (f32x4){0,0,0,0}; acc[ct][1] = (f32x4){0,0,0,0}; }
    float zp0 = 0.f, zp1 = 0.f;

    for (int jp = 0; jp <= wid; ++jp) {
      i64 aS[2][2];
      #pragma unroll
      for (int jtl = 0; jtl < 2; ++jtl) {
        int arow = jp * 32 + jtl * 16 + li;
        aS[jtl][0] = ld8f8(&A2[qf_idx(arow, g * 8)]);
        aS[jtl][1] = ld8f8(&A2[qf_idx(arow, 32 + g * 8)]);
      }
      #pragma unroll
      for (int jtl = 0; jtl < 2; ++jtl)
        #pragma unroll
        for (int itl = 0; itl < 2; ++itl) {
          f32x4 s = {0.f, 0.f, 0.f, 0.f};
          s = MFMA8(aS[jtl][0], bQ[itl][0], s);
          s = MFMA8(aS[jtl][1], bQ[itl][1], s);
          int ii = j0 + itl * 16 + li;
          float p4[4]; float ps = 0.f;
          #pragma unroll
          for (int r = 0; r < 4; ++r) {
            int jidx = jp * 32 + jtl * 16 + 4 * g + r;
            p4[r] = (jidx <= ii) ? __expf(s[r] * 0.125f) : 0.f;
            ps += p4[r];
          }
          if (itl == 0) zp0 += ps; else zp1 += ps;
          *(uint32_t*)&Pw[(itl * 16 + li) * 40 + jtl * 16 + 4 * g] =
              pk4f8(p4[0], p4[1], p4[2], p4[3]);
        }
      asm volatile("" ::: "memory");   // order P reads after P writes
      i64 aV[4];
      #pragma unroll
      for (int ct = 0; ct < 4; ++ct)
        aV[ct] = ld8f8(&A2[16384 + vf_idx(ct * 16 + li, jp * 32 + g * 8)]);
      #pragma unroll
      for (int itl = 0; itl < 2; ++itl) {
        i64 bP = ldP(&Pw[(itl * 16 + li) * 40 + g * 8]);
        #pragma unroll
        for (int ct = 0; ct < 4; ++ct)
          acc[ct][itl] = MFMA8(aV[ct], bP, acc[ct][itl]);
      }
    }
    zp0 += __shfl_xor(zp0, 16); zp0 += __shfl_xor(zp0, 32);
    zp1 += __shfl_xor(zp1, 16); zp1 += __shfl_xor(zp1, 32);
    #pragma unroll
    for (int itl = 0; itl < 2; ++itl) {
      float invz = 1.0f / (itl == 0 ? zp0 : zp1);
      int i = j0 + itl * 16 + li;
      #pragma unroll
      for (int ct = 0; ct < 4; ++ct)
        #pragma unroll
        for (int r = 0; r < 4; ++r) {
          int c = ct * 16 + 4 * g + r;
          outL[(size_t)c * HW + i] =
              fmaf(beta3[c], acc[ct][itl][r] * invz, xl[(size_t)c * HW + i]);
        }
    }
  }
}

extern "C" void kernel_launch(void* const* d_in, const int* in_sizes, int n_in,
                              void* d_out, int out_size, void* d_ws, size_t ws_size,
                              hipStream_t stream) {
  const float* x       = (const float*)d_in[0];
  const float* res_enc = (const float*)d_in[1];
  const float* tr_feat = (const float*)d_in[2];
  const float* Wl1     = (const float*)d_in[3];
  const float* bl1     = (const float*)d_in[4];
  const float* Wr1     = (const float*)d_in[5];
  const float* br1     = (const float*)d_in[6];
  const float* Wl2     = (const float*)d_in[7];
  const float* bl2     = (const float*)d_in[8];
  const float* Wr2     = (const float*)d_in[9];
  const float* br2     = (const float*)d_in[10];
  const float* beta1   = (const float*)d_in[11];
  const float* gamma1  = (const float*)d_in[12];
  const float* beta3   = (const float*)d_in[13];
  const float* gamma3  = (const float*)d_in[14];
  float* outp = (float*)d_out;

  dim3 grid(512);    // 2 left-batches x 256 rows
  dim3 block(512);   // 8 waves, one 32-pixel column tile each
  SCAM_73151882985874_kernel<<<grid, block, 0, stream>>>(
      x, res_enc, tr_feat, Wl1, bl1, Wr1, br1, Wl2, bl2, Wr2, br2,
      beta1, gamma1, beta3, gamma3, outp);
}

// Round 7
// 80.702 us; speedup vs baseline: 1.9572x; 1.9572x over previous
//
#include <hip/hip_runtime.h>
#include <stdint.h>

#define HW 65536   // 256*256
#define C_ 64

typedef __attribute__((ext_vector_type(8))) short short8;
typedef __attribute__((ext_vector_type(4))) float f32x4;
typedef long long i64;

#define MFMA16(a, b, c) __builtin_amdgcn_mfma_f32_16x16x32_bf16((a), (b), (c), 0, 0, 0)
#define MFMA8(a, b, c)  __builtin_amdgcn_mfma_f32_16x16x32_fp8_fp8((a), (b), (c), 0, 0, 0)

union U16x8 { uint4 q; short8 v; uint32_t u[4]; };
union PU { uint32_t u[2]; i64 q; };

__device__ inline uint32_t pack_bf16(float lo, float hi) {
  uint32_t ul = __float_as_uint(lo), uh = __float_as_uint(hi);
  ul = (ul + 0x7fffu + ((ul >> 16) & 1u)) >> 16;
  uh = (uh + 0x7fffu + ((uh >> 16) & 1u)) >> 16;
  return ul | (uh << 16);
}
__device__ inline short8 ld8bf(const uint16_t* p) {
  U16x8 t; t.q = *(const uint4*)p; return t.v;
}
__device__ inline i64 ld8f8(const uint8_t* p) { return *(const i64*)p; }
// P loads use the SAME type as P stores (uint32_t) -> TBAA keeps program order
__device__ inline i64 ldP(const uint8_t* p) {
  PU t;
  t.u[0] = *(const uint32_t*)p;
  t.u[1] = *(const uint32_t*)(p + 4);
  return t.q;
}
__device__ inline uint32_t pk4f8(float a, float b, float c, float d) {
  uint32_t v = __builtin_amdgcn_cvt_pk_fp8_f32(a, b, 0, false);
  v = __builtin_amdgcn_cvt_pk_fp8_f32(c, d, v, true);
  return v;
}

// bf16 X tile: elem index, XOR swizzle (8-elem granule)
__device__ inline int xb_idx(int p, int c) { return (p * 64 + c) ^ ((p & 7) << 3); }
// fp8 Q/S tile: byte index [pix][c]
__device__ inline int qf_idx(int p, int c) { return p * 64 + (c ^ ((p & 7) << 3)); }
// fp8 V tile: byte offset [c][j]
__device__ inline int vf_idx(int c, int j) { return c * 256 + (j ^ ((c & 7) << 3)); }

// NOTE: second arg 2 (NOT 4): (.,4) makes the allocator target 64 VGPRs and
// spill (round 6: FETCH +148MB of scratch). With <=128 VGPRs + 74KB LDS the
// HW reaches 2 blocks/CU on its own.
__global__ __launch_bounds__(512, 2) void SCAM_73151882985874_kernel(
    const float* __restrict__ x, const float* __restrict__ res_enc,
    const float* __restrict__ tr_feat,
    const float* __restrict__ Wl1, const float* __restrict__ bl1,
    const float* __restrict__ Wr1, const float* __restrict__ br1,
    const float* __restrict__ Wl2, const float* __restrict__ bl2,
    const float* __restrict__ Wr2, const float* __restrict__ br2,
    const float* __restrict__ beta1, const float* __restrict__ gamma1,
    const float* __restrict__ beta3, const float* __restrict__ gamma3,
    float* __restrict__ out)
{
  // A1: xl bf16 [pix][c] (32KB)  ->  Q fp8 [pix][c] (16KB) | bufL fp8 [c][j] (16KB)
  // A2: xr bf16 [pix][c] (32KB)  ->  S fp8 [pix][c] (16KB) | bufR fp8 [c][j] (16KB)
  __shared__ __align__(16) uint8_t A1[32768];
  __shared__ __align__(16) uint8_t A2[32768];
  __shared__ __align__(16) uint8_t sP8[10240];   // per-wave P fp8: 8 x [32 cols][40 B]

  const int tid = threadIdx.x;
  const int wid = tid >> 6, lane = tid & 63, g = lane >> 4, li = lane & 15;
  const int bb = blockIdx.x >> 8, hh = blockIdx.x & 255;
  const float yy = (float)hh * (2.0f / 255.0f) - 1.0f;
  const float rr = fabsf(yy - 0.5f);

  const size_t rowoff = (size_t)hh * 256;
  const float* xl  = x + ((size_t)bb * C_) * HW + rowoff;
  const float* xr  = x + ((size_t)(2 + bb) * C_) * HW + rowoff;
  const float* trl = tr_feat + ((size_t)bb * C_) * HW + rowoff;
  const float* trr = tr_feat + ((size_t)(2 + bb) * C_) * HW + rowoff;
  const float* rel = res_enc + ((size_t)bb * C_) * HW + rowoff;
  const float* rer = res_enc + ((size_t)(2 + bb) * C_) * HW + rowoff;
  float* outL = out + ((size_t)bb * C_) * HW + rowoff;
  float* outR = out + ((size_t)(2 + bb) * C_) * HW + rowoff;

  // ---------- Phase A: stage xl -> A1, xr -> A2 (f32 -> bf16 [pix][c]) ----------
  {
    const int side = tid >> 8;
    const int p    = tid & 255;
    const float* src = side ? xr : xl;
    uint16_t* dst = (uint16_t*)(side ? A2 : A1);
    #pragma unroll
    for (int cb = 0; cb < 8; ++cb) {
      int c0 = cb * 8;
      const float* s = src + (size_t)c0 * HW + p;
      U16x8 t8;
      t8.u[0] = pack_bf16(s[0],              s[(size_t)HW]);
      t8.u[1] = pack_bf16(s[2 * (size_t)HW], s[3 * (size_t)HW]);
      t8.u[2] = pack_bf16(s[4 * (size_t)HW], s[5 * (size_t)HW]);
      t8.u[3] = pack_bf16(s[6 * (size_t)HW], s[7 * (size_t)HW]);
      *(uint4*)&dst[xb_idx(p, c0)] = t8.q;
    }
  }
  __syncthreads();

  // own-X fragments -> regs (must complete block-wide before fp8 overwrites)
  short8 bxL[2][2], bxR[2][2];
  #pragma unroll
  for (int ptl = 0; ptl < 2; ++ptl) {
    int pix = wid * 32 + ptl * 16 + li;
    bxL[ptl][0] = ld8bf(&((const uint16_t*)A1)[xb_idx(pix, g * 8)]);
    bxL[ptl][1] = ld8bf(&((const uint16_t*)A1)[xb_idx(pix, 32 + g * 8)]);
    bxR[ptl][0] = ld8bf(&((const uint16_t*)A2)[xb_idx(pix, g * 8)]);
    bxR[ptl][1] = ld8bf(&((const uint16_t*)A2)[xb_idx(pix, 32 + g * 8)]);
  }
  __syncthreads();

  // ---------- Phase B: four 1x1 convs (bf16 MFMA), outputs quantized to fp8 ----------
  auto conv_one = [&](const float* __restrict__ Wm, int ldw,
                      const float* __restrict__ bias, const float* __restrict__ mod,
                      const float* __restrict__ E, int coord,
                      const short8 bx[2][2], uint8_t* dstQS, uint8_t* dstV) {
    #pragma unroll
    for (int ct = 0; ct < 4; ++ct) {
      // per-ct W fragments / bias / modulation (short live ranges)
      short8 af0, af1;
      {
        const float* wr = Wm + (size_t)(ct * 16 + li) * ldw + g * 8;
        U16x8 t8;
        t8.u[0] = pack_bf16(wr[0], wr[1]); t8.u[1] = pack_bf16(wr[2], wr[3]);
        t8.u[2] = pack_bf16(wr[4], wr[5]); t8.u[3] = pack_bf16(wr[6], wr[7]);
        af0 = t8.v;
        const float* w2 = wr + 32;
        t8.u[0] = pack_bf16(w2[0], w2[1]); t8.u[1] = pack_bf16(w2[2], w2[3]);
        t8.u[2] = pack_bf16(w2[4], w2[5]); t8.u[3] = pack_bf16(w2[6], w2[7]);
        af1 = t8.v;
      }
      float be[4], md[4];
      #pragma unroll
      for (int r = 0; r < 4; ++r) {
        int c = ct * 16 + 4 * g + r;
        float b = bias[c];
        if (coord) b += Wm[(size_t)c * ldw + 64] * yy + Wm[(size_t)c * ldw + 65] * rr;
        be[r] = b;
        md[r] = mod[c];
      }
      #pragma unroll
      for (int ptl = 0; ptl < 2; ++ptl) {
        int pix = wid * 32 + ptl * 16 + li;
        float ev[4];
        #pragma unroll
        for (int r = 0; r < 4; ++r)
          ev[r] = E[(size_t)(ct * 16 + 4 * g + r) * HW + pix];
        f32x4 acc = {0.f, 0.f, 0.f, 0.f};
        acc = MFMA16(af0, bx[ptl][0], acc);
        acc = MFMA16(af1, bx[ptl][1], acc);
        float v[4];
        #pragma unroll
        for (int r = 0; r < 4; ++r) v[r] = acc[r] + be[r] + md[r] * ev[r];
        if (dstV) {
          uint32_t pk = pk4f8(v[0], v[1], v[2], v[3]);
          #pragma unroll
          for (int r = 0; r < 4; ++r)
            dstV[vf_idx(ct * 16 + 4 * g + r, pix)] = (uint8_t)(pk >> (8 * r));
        } else {
          *(uint32_t*)&dstQS[qf_idx(pix, ct * 16 + 4 * g)] = pk4f8(v[0], v[1], v[2], v[3]);
        }
      }
    }
  };

  conv_one(Wl1, 66, bl1, beta1,  trl, 1, bxL, A1, nullptr);         // Q   (fp8, unscaled)
  conv_one(Wr1, 66, br1, beta1,  trr, 1, bxR, A2, nullptr);         // S
  conv_one(Wl2, 64, bl2, gamma1, rel, 0, bxL, nullptr, A1 + 16384); // bufL
  conv_one(Wr2, 64, br2, gamma1, rer, 0, bxR, nullptr, A2 + 16384); // bufR
  __syncthreads();

  uint8_t* Pw = &sP8[wid * 1280];
  const int j0 = wid * 32;

  // ---------- pass 2: out_R cols = own 32 pixels; sum over a >= col ----------
  {
    i64 bS[2][2];
    #pragma unroll
    for (int jt = 0; jt < 2; ++jt) {
      int p = j0 + jt * 16 + li;
      bS[jt][0] = ld8f8(&A2[qf_idx(p, g * 8)]);
      bS[jt][1] = ld8f8(&A2[qf_idx(p, 32 + g * 8)]);
    }
    f32x4 acc[4][2];
    #pragma unroll
    for (int ct = 0; ct < 4; ++ct) { acc[ct][0] = (f32x4){0,0,0,0}; acc[ct][1] = (f32x4){0,0,0,0}; }
    float zp0 = 0.f, zp1 = 0.f;

    for (int ip = wid; ip < 8; ++ip) {
      i64 aQ[2][2];
      #pragma unroll
      for (int itl = 0; itl < 2; ++itl) {
        int arow = ip * 32 + itl * 16 + li;
        aQ[itl][0] = ld8f8(&A1[qf_idx(arow, g * 8)]);
        aQ[itl][1] = ld8f8(&A1[qf_idx(arow, 32 + g * 8)]);
      }
      #pragma unroll
      for (int itl = 0; itl < 2; ++itl)
        #pragma unroll
        for (int jt = 0; jt < 2; ++jt) {
          f32x4 s = {0.f, 0.f, 0.f, 0.f};
          s = MFMA8(aQ[itl][0], bS[jt][0], s);
          s = MFMA8(aQ[itl][1], bS[jt][1], s);
          int jj = j0 + jt * 16 + li;
          float p4[4]; float ps = 0.f;
          #pragma unroll
          for (int r = 0; r < 4; ++r) {
            int aidx = ip * 32 + itl * 16 + 4 * g + r;
            p4[r] = (aidx >= jj) ? __expf(s[r] * 0.125f) : 0.f;
            ps += p4[r];
          }
          if (jt == 0) zp0 += ps; else zp1 += ps;
          *(uint32_t*)&Pw[(jt * 16 + li) * 40 + itl * 16 + 4 * g] =
              pk4f8(p4[0], p4[1], p4[2], p4[3]);
        }
      asm volatile("" ::: "memory");   // order P reads after P writes
      i64 aV[4];
      #pragma unroll
      for (int ct = 0; ct < 4; ++ct)
        aV[ct] = ld8f8(&A1[16384 + vf_idx(ct * 16 + li, ip * 32 + g * 8)]);
      #pragma unroll
      for (int jt = 0; jt < 2; ++jt) {
        i64 bP = ldP(&Pw[(jt * 16 + li) * 40 + g * 8]);
        #pragma unroll
        for (int ct = 0; ct < 4; ++ct)
          acc[ct][jt] = MFMA8(aV[ct], bP, acc[ct][jt]);
      }
    }
    zp0 += __shfl_xor(zp0, 16); zp0 += __shfl_xor(zp0, 32);
    zp1 += __shfl_xor(zp1, 16); zp1 += __shfl_xor(zp1, 32);
    #pragma unroll
    for (int jt = 0; jt < 2; ++jt) {
      float invz = 1.0f / (jt == 0 ? zp0 : zp1);
      int j = j0 + jt * 16 + li;
      #pragma unroll
      for (int ct = 0; ct < 4; ++ct)
        #pragma unroll
        for (int r = 0; r < 4; ++r) {
          int c = ct * 16 + 4 * g + r;
          outR[(size_t)c * HW + j] =
              fmaf(gamma3[c], acc[ct][jt][r] * invz, xr[(size_t)c * HW + j]);
        }
    }
  }

  // ---------- pass 1: out_L cols = own 32 pixels; sum over a <= col ----------
  // (no barrier: Q/S/V regions read-only since conv barrier; Pw wave-private)
  {
    i64 bQ[2][2];
    #pragma unroll
    for (int itl = 0; itl < 2; ++itl) {
      int p = j0 + itl * 16 + li;
      bQ[itl][0] = ld8f8(&A1[qf_idx(p, g * 8)]);
      bQ[itl][1] = ld8f8(&A1[qf_idx(p, 32 + g * 8)]);
    }
    f32x4 acc[4][2];
    #pragma unroll
    for (int ct = 0; ct < 4; ++ct) { acc[ct][0] = (f32x4){0,0,0,0}; acc[ct][1] = (f32x4){0,0,0,0}; }
    float zp0 = 0.f, zp1 = 0.f;

    for (int jp = 0; jp <= wid; ++jp) {
      i64 aS[2][2];
      #pragma unroll
      for (int jtl = 0; jtl < 2; ++jtl) {
        int arow = jp * 32 + jtl * 16 + li;
        aS[jtl][0] = ld8f8(&A2[qf_idx(arow, g * 8)]);
        aS[jtl][1] = ld8f8(&A2[qf_idx(arow, 32 + g * 8)]);
      }
      #pragma unroll
      for (int jtl = 0; jtl < 2; ++jtl)
        #pragma unroll
        for (int itl = 0; itl < 2; ++itl) {
          f32x4 s = {0.f, 0.f, 0.f, 0.f};
          s = MFMA8(aS[jtl][0], bQ[itl][0], s);
          s = MFMA8(aS[jtl][1], bQ[itl][1], s);
          int ii = j0 + itl * 16 + li;
          float p4[4]; float ps = 0.f;
          #pragma unroll
          for (int r = 0; r < 4; ++r) {
            int jidx = jp * 32 + jtl * 16 + 4 * g + r;
            p4[r] = (jidx <= ii) ? __expf(s[r] * 0.125f) : 0.f;
            ps += p4[r];
          }
          if (itl == 0) zp0 += ps; else zp1 += ps;
          *(uint32_t*)&Pw[(itl * 16 + li) * 40 + jtl * 16 + 4 * g] =
              pk4f8(p4[0], p4[1], p4[2], p4[3]);
        }
      asm volatile("" ::: "memory");   // order P reads after P writes
      i64 aV[4];
      #pragma unroll
      for (int ct = 0; ct < 4; ++ct)
        aV[ct] = ld8f8(&A2[16384 + vf_idx(ct * 16 + li, jp * 32 + g * 8)]);
      #pragma unroll
      for (int itl = 0; itl < 2; ++itl) {
        i64 bP = ldP(&Pw[(itl * 16 + li) * 40 + g * 8]);
        #pragma unroll
        for (int ct = 0; ct < 4; ++ct)
          acc[ct][itl] = MFMA8(aV[ct], bP, acc[ct][itl]);
      }
    }
    zp0 += __shfl_xor(zp0, 16); zp0 += __shfl_xor(zp0, 32);
    zp1 += __shfl_xor(zp1, 16); zp1 += __shfl_xor(zp1, 32);
    #pragma unroll
    for (int itl = 0; itl < 2; ++itl) {
      float invz = 1.0f / (itl == 0 ? zp0 : zp1);
      int i = j0 + itl * 16 + li;
      #pragma unroll
      for (int ct = 0; ct < 4; ++ct)
        #pragma unroll
        for (int r = 0; r < 4; ++r) {
          int c = ct * 16 + 4 * g + r;
          outL[(size_t)c * HW + i] =
              fmaf(beta3[c], acc[ct][itl][r] * invz, xl[(size_t)c * HW + i]);
        }
    }
  }
}

extern "C" void kernel_launch(void* const* d_in, const int* in_sizes, int n_in,
                              void* d_out, int out_size, void* d_ws, size_t ws_size,
                              hipStream_t stream) {
  const float* x       = (const float*)d_in[0];
  const float* res_enc = (const float*)d_in[1];
  const float* tr_feat = (const float*)d_in[2];
  const float* Wl1     = (const float*)d_in[3];
  const float* bl1     = (const float*)d_in[4];
  const float* Wr1     = (const float*)d_in[5];
  const float* br1     = (const float*)d_in[6];
  const float* Wl2     = (const float*)d_in[7];
  const float* bl2     = (const float*)d_in[8];
  const float* Wr2     = (const float*)d_in[9];
  const float* br2     = (const float*)d_in[10];
  const float* beta1   = (const float*)d_in[11];
  const float* gamma1  = (const float*)d_in[12];
  const float* beta3   = (const float*)d_in[13];
  const float* gamma3  = (const float*)d_in[14];
  float* outp = (float*)d_out;

  dim3 grid(512);    // 2 left-batches x 256 rows
  dim3 block(512);   // 8 waves, one 32-pixel column tile each
  SCAM_73151882985874_kernel<<<grid, block, 0, stream>>>(
      x, res_enc, tr_feat, Wl1, bl1, Wr1, br1, Wl2, bl2, Wr2, br2,
      beta1, gamma1, beta3, gamma3, outp);
}